// Round 7
// baseline (19.242 us; speedup 1.0000x reference)
//
#include <hip/hip_runtime.h>

#define B_SZ  64
#define L_SZ  4096
#define VOCAB 33
#define D_SZ  256
#define MAGIC 0x3C6EF372u

// ws layout
//   part  : float [64][4][256]   (producer partial pre-activations)
//   flags : uint  [64*4]         (publish flags, after part)
#define PART_FLOATS (B_SZ * 4 * D_SZ)

__global__ __launch_bounds__(512) void prot_fused(
    const int* __restrict__ X,
    const int* __restrict__ valid_lens,
    const float* __restrict__ emb,
    const float* __restrict__ W1,
    const float* __restrict__ b1,
    const float* __restrict__ W2,
    const float* __restrict__ b2,
    float* __restrict__ out,
    float* __restrict__ ws)
{
    float*        part  = ws;
    unsigned int* flags = (unsigned int*)(ws + PART_FLOATS);

    const int bid = blockIdx.x;
    const int t   = threadIdx.x;

    if (bid < 256) {
        // ================= producer: (b, kg) =================
        const int b  = bid >> 2;
        const int kg = bid & 3;           // k-slice [kg*64, kg*64+64)

        __shared__ int   s_c[8][VOCAB];
        __shared__ float s_cntf[VOCAB];
        __shared__ float s_pool[64];
        __shared__ float s_red[2][D_SZ];

        const int wv = t >> 6;
        if (t < 8 * VOCAB) ((int*)s_c)[t] = 0;
        __syncthreads();

        // ---- histogram of row b over valid prefix ----
        const int   vl = valid_lens[b];
        const int4* x4 = reinterpret_cast<const int4*>(X + (size_t)b * L_SZ);
        const int4  u0 = x4[t];
        const int4  u1 = x4[t + 512];
        const int   l0 = t * 4;
        const int   l1 = (t + 512) * 4;
        if (l0 + 0 < vl) atomicAdd(&s_c[wv][u0.x], 1);
        if (l0 + 1 < vl) atomicAdd(&s_c[wv][u0.y], 1);
        if (l0 + 2 < vl) atomicAdd(&s_c[wv][u0.z], 1);
        if (l0 + 3 < vl) atomicAdd(&s_c[wv][u0.w], 1);
        if (l1 + 0 < vl) atomicAdd(&s_c[wv][u1.x], 1);
        if (l1 + 1 < vl) atomicAdd(&s_c[wv][u1.y], 1);
        if (l1 + 2 < vl) atomicAdd(&s_c[wv][u1.z], 1);
        if (l1 + 3 < vl) atomicAdd(&s_c[wv][u1.w], 1);
        __syncthreads();

        if (t < VOCAB) {
            int c = 0;
            #pragma unroll
            for (int w = 0; w < 8; ++w) c += s_c[w][t];
            s_cntf[t] = (float)c;
        }
        __syncthreads();

        // ---- pooled on this block's k-slice only ----
        if (t < 64) {
            float p = 0.f;
            #pragma unroll
            for (int v = 0; v < VOCAB; ++v)
                p = fmaf(s_cntf[v], emb[v * D_SZ + kg * 64 + t], p);
            s_pool[t] = p;
        }
        __syncthreads();

        // ---- partial[j] = sum_{k in slice} pooled[k] * W1[k, j], 2-way split ----
        const int j  = t & 255;
        const int h2 = t >> 8;            // 0..1
        float acc = 0.f;
        #pragma unroll
        for (int i = 0; i < 32; ++i) {
            const int k = kg * 64 + h2 * 32 + i;
            acc = fmaf(s_pool[h2 * 32 + i], W1[k * D_SZ + j], acc);
        }
        s_red[h2][j] = acc;
        __syncthreads();

        if (t < D_SZ) {
            const float pr = s_red[0][t] + s_red[1][t];
            __hip_atomic_store(&part[(b * 4 + kg) * D_SZ + t], pr,
                               __ATOMIC_RELAXED, __HIP_MEMORY_SCOPE_AGENT);
        }
        __syncthreads();
        if (t == 0)
            __hip_atomic_store(&flags[b * 4 + kg], MAGIC,
                               __ATOMIC_RELEASE, __HIP_MEMORY_SCOPE_AGENT);
    } else {
        // ================= consumer: (b, cg) =================
        const int cb = bid - 256;
        const int b  = cb >> 2;
        const int cg = cb & 3;            // output cols [cg*64, cg*64+64)
        const int kk = t >> 6;            // 0..7
        const int c  = t & 63;

        __shared__ float s_h[D_SZ];
        __shared__ float s_p[8][64];

        // ---- prefetch W2 col-slice; latency hides under the spin ----
        float w2[32];
        #pragma unroll
        for (int q = 0; q < 32; ++q)
            w2[q] = W2[(kk * 32 + q) * D_SZ + cg * 64 + c];
        const float bias1 = (t < D_SZ) ? b1[t] : 0.f;

        // ---- wait for row b's 4 producer slots ----
        if (t == 0) {
            for (;;) {
                bool ok = true;
                #pragma unroll
                for (int q = 0; q < 4; ++q)
                    ok &= (__hip_atomic_load(&flags[b * 4 + q], __ATOMIC_ACQUIRE,
                                             __HIP_MEMORY_SCOPE_AGENT) == MAGIC);
                if (ok) break;
                __builtin_amdgcn_s_sleep(8);
            }
        }
        __syncthreads();

        // ---- h = relu(b1 + sum of 4 partials), fixed order ----
        if (t < D_SZ) {
            float a = bias1;
            #pragma unroll
            for (int q = 0; q < 4; ++q)
                a += __hip_atomic_load(&part[(b * 4 + q) * D_SZ + t],
                                       __ATOMIC_RELAXED, __HIP_MEMORY_SCOPE_AGENT);
            s_h[t] = fmaxf(a, 0.f);
        }
        __syncthreads();

        // ---- layer 2 from registers, k-split 8 ----
        float acc = 0.f;
        #pragma unroll
        for (int q = 0; q < 32; ++q)
            acc = fmaf(s_h[kk * 32 + q], w2[q], acc);
        s_p[kk][c] = acc;
        __syncthreads();

        if (t < 64) {
            float o = b2[cg * 64 + t];
            #pragma unroll
            for (int q = 0; q < 8; ++q) o += s_p[q][t];
            out[(size_t)b * D_SZ + cg * 64 + t] = fmaxf(o, 0.f);
        }
    }
}

extern "C" void kernel_launch(void* const* d_in, const int* in_sizes, int n_in,
                              void* d_out, int out_size, void* d_ws, size_t ws_size,
                              hipStream_t stream) {
    const int*   X          = (const int*)d_in[0];
    const int*   valid_lens = (const int*)d_in[1];
    const float* emb        = (const float*)d_in[2];
    const float* W1         = (const float*)d_in[3];
    const float* b1         = (const float*)d_in[4];
    const float* W2         = (const float*)d_in[5];
    const float* b2         = (const float*)d_in[6];
    float* out = (float*)d_out;
    float* ws  = (float*)d_ws;

    prot_fused<<<512, 512, 0, stream>>>(X, valid_lens, emb, W1, b1, W2, b2, out, ws);
}

// Round 8
// 10.955 us; speedup vs baseline: 1.7564x; 1.7564x over previous
//
#include <hip/hip_runtime.h>

#define B_SZ  64
#define L_SZ  4096
#define VOCAB 33
#define D_SZ  256
#define NT    512    // threads per block (8 waves)
#define NW    8      // waves per block
#define C     64     // float4 columns of a 256-wide row

// Grid: 256 blocks = (b = bid>>2, cg = bid&3). Each block computes the full
// hidden vector h[256] for row b (W1 is L2-resident; 4x redundancy is cheap)
// but only its own 64-column W2 slice, prefetched into registers at entry.
__global__ __launch_bounds__(NT) void prot_fused(
    const int* __restrict__ X,
    const int* __restrict__ valid_lens,
    const float* __restrict__ emb,
    const float* __restrict__ W1,
    const float* __restrict__ b1,
    const float* __restrict__ W2,
    const float* __restrict__ b2,
    float* __restrict__ out)
{
    __shared__ int    s_cnt[NW][VOCAB];
    __shared__ float4 s_part[NW][C];
    __shared__ float  s_vec[D_SZ];        // pooled, then h

    const int bid = blockIdx.x;
    const int b   = bid >> 2;
    const int cg  = bid & 3;              // output cols [cg*64, cg*64+64)
    const int t   = threadIdx.x;
    const int g   = t >> 6;               // wave id == k/v group, 0..7
    const int c   = t & 63;

    const float4* emb4 = reinterpret_cast<const float4*>(emb);
    const float4* W14  = reinterpret_cast<const float4*>(W1);

    // ---- prefetch W2 column-slice into regs (64 KB/block, 32 regs/thread);
    //      latency hides under histogram + pool + layer 1 ----
    float w2[32];
    #pragma unroll
    for (int q = 0; q < 32; ++q)
        w2[q] = W2[(g * 32 + q) * D_SZ + cg * 64 + c];

    // ---- prefetch emb slice for pooled (wave g covers vocab g*4..g*4+3, +32) ----
    float4 e4[4];
    #pragma unroll
    for (int j = 0; j < 4; ++j)
        e4[j] = emb4[(g * 4 + j) * C + c];
    float4 e32 = make_float4(0.f, 0.f, 0.f, 0.f);
    if (g == 0) e32 = emb4[32 * C + c];

    float4 bias1 = make_float4(0.f, 0.f, 0.f, 0.f);
    if (t < C) bias1 = reinterpret_cast<const float4*>(b1)[t];
    const float bias2 = (t < 64) ? b2[cg * 64 + t] : 0.f;

    const int   vl    = valid_lens[b];
    const int4* xrow4 = reinterpret_cast<const int4*>(X + (size_t)b * L_SZ);
    const int4  t0    = xrow4[t];
    const int4  t1    = xrow4[t + NT];

    // ---- per-wave privatized histogram ----
    if (t < NW * VOCAB) ((int*)s_cnt)[t] = 0;
    __syncthreads();

    const int l0 = t * 4;
    const int l1 = (t + NT) * 4;
    if (l0 + 0 < vl) atomicAdd(&s_cnt[g][t0.x], 1);
    if (l0 + 1 < vl) atomicAdd(&s_cnt[g][t0.y], 1);
    if (l0 + 2 < vl) atomicAdd(&s_cnt[g][t0.z], 1);
    if (l0 + 3 < vl) atomicAdd(&s_cnt[g][t0.w], 1);
    if (l1 + 0 < vl) atomicAdd(&s_cnt[g][t1.x], 1);
    if (l1 + 1 < vl) atomicAdd(&s_cnt[g][t1.y], 1);
    if (l1 + 2 < vl) atomicAdd(&s_cnt[g][t1.z], 1);
    if (l1 + 3 < vl) atomicAdd(&s_cnt[g][t1.w], 1);
    __syncthreads();

    // ---- per-thread count gather (LDS broadcast reads) ----
    float cf[4];
    #pragma unroll
    for (int j = 0; j < 4; ++j) {
        int s = 0;
        #pragma unroll
        for (int w = 0; w < NW; ++w) s += s_cnt[w][g * 4 + j];
        cf[j] = (float)s;
    }
    float c32 = 0.f;
    if (g == 0) {
        int s = 0;
        #pragma unroll
        for (int w = 0; w < NW; ++w) s += s_cnt[w][32];
        c32 = (float)s;
    }

    // ---- pooled partial over this wave's vocab slice ----
    float4 p = make_float4(0.f, 0.f, 0.f, 0.f);
    #pragma unroll
    for (int j = 0; j < 4; ++j) {
        p.x = fmaf(cf[j], e4[j].x, p.x);
        p.y = fmaf(cf[j], e4[j].y, p.y);
        p.z = fmaf(cf[j], e4[j].z, p.z);
        p.w = fmaf(cf[j], e4[j].w, p.w);
    }
    p.x = fmaf(c32, e32.x, p.x);
    p.y = fmaf(c32, e32.y, p.y);
    p.z = fmaf(c32, e32.z, p.z);
    p.w = fmaf(c32, e32.w, p.w);
    s_part[g][c] = p;
    __syncthreads();

    if (t < C) {
        float4 s = s_part[0][t];
        #pragma unroll
        for (int g2 = 1; g2 < NW; ++g2) {
            float4 q = s_part[g2][t];
            s.x += q.x; s.y += q.y; s.z += q.z; s.w += q.w;
        }
        reinterpret_cast<float4*>(s_vec)[t] = s;
    }
    __syncthreads();

    // ---- layer 1 (full 256 cols): k in [g*32, g*32+32), float4 W1 loads ----
    float4 acc = make_float4(0.f, 0.f, 0.f, 0.f);
    #pragma unroll
    for (int j = 0; j < 32; ++j) {
        const int   k  = g * 32 + j;
        const float sv = s_vec[k];
        const float4 w = W14[k * C + c];
        acc.x = fmaf(sv, w.x, acc.x);
        acc.y = fmaf(sv, w.y, acc.y);
        acc.z = fmaf(sv, w.z, acc.z);
        acc.w = fmaf(sv, w.w, acc.w);
    }
    s_part[g][c] = acc;
    __syncthreads();

    if (t < C) {
        float4 h = bias1;
        #pragma unroll
        for (int g2 = 0; g2 < NW; ++g2) {
            float4 q = s_part[g2][t];
            h.x += q.x; h.y += q.y; h.z += q.z; h.w += q.w;
        }
        h.x = fmaxf(h.x, 0.f); h.y = fmaxf(h.y, 0.f);
        h.z = fmaxf(h.z, 0.f); h.w = fmaxf(h.w, 0.f);
        reinterpret_cast<float4*>(s_vec)[t] = h;
    }
    __syncthreads();

    // ---- layer 2 from registers: 64-column slice, k-split 8 ----
    float acc2 = 0.f;
    #pragma unroll
    for (int q = 0; q < 32; ++q)
        acc2 = fmaf(s_vec[g * 32 + q], w2[q], acc2);
    // reuse s_part as [8][64] scalar scratch
    ((float*)s_part)[g * 64 + c] = acc2;
    __syncthreads();

    if (t < 64) {
        float o = bias2;
        #pragma unroll
        for (int q = 0; q < NW; ++q) o += ((float*)s_part)[q * 64 + t];
        out[(size_t)b * D_SZ + cg * 64 + t] = fmaxf(o, 0.f);
    }
}

extern "C" void kernel_launch(void* const* d_in, const int* in_sizes, int n_in,
                              void* d_out, int out_size, void* d_ws, size_t ws_size,
                              hipStream_t stream) {
    const int*   X          = (const int*)d_in[0];
    const int*   valid_lens = (const int*)d_in[1];
    const float* emb        = (const float*)d_in[2];
    const float* W1         = (const float*)d_in[3];
    const float* b1         = (const float*)d_in[4];
    const float* W2         = (const float*)d_in[5];
    const float* b2         = (const float*)d_in[6];
    float* out = (float*)d_out;

    prot_fused<<<256, NT, 0, stream>>>(X, valid_lens, emb, W1, b1, W2, b2, out);
}

// Round 9
// 10.321 us; speedup vs baseline: 1.8643x; 1.0614x over previous
//
#include <hip/hip_runtime.h>

#define B_SZ  64
#define L_SZ  4096
#define VOCAB 33
#define D_SZ  256
#define NT    512    // threads per block (8 waves)
#define NW    8      // waves per block
#define C     64     // float4 columns of a 256-wide row

// lgkm-only barrier: cross-wave LDS visibility WITHOUT draining vmcnt,
// so the in-flight W1/W2 register prefetch streams across it.
#define LBAR()                                            \
    do {                                                  \
        asm volatile("s_waitcnt lgkmcnt(0)" ::: "memory");\
        __builtin_amdgcn_s_barrier();                     \
        __builtin_amdgcn_sched_barrier(0);                \
    } while (0)

// Grid: 256 blocks = (b = bid>>2, cg = bid&3). Full hidden vector per block
// (W1 L2-resident), 64-col W2 slice. ALL weights prefetched into registers;
// no barrier in the kernel drains vmcnt, so the weight streams overlap the
// histogram/pool phases and the first drain is layer-1's register use.
__global__ __launch_bounds__(NT) void prot_fused(
    const int* __restrict__ X,
    const int* __restrict__ valid_lens,
    const float* __restrict__ emb,
    const float* __restrict__ W1,
    const float* __restrict__ b1,
    const float* __restrict__ W2,
    const float* __restrict__ b2,
    float* __restrict__ out)
{
    __shared__ int    s_cnt[NW][VOCAB];
    __shared__ float4 s_part[NW][C];
    __shared__ float  s_vec[D_SZ];        // pooled, then h

    const int bid = blockIdx.x;
    const int b   = bid >> 2;
    const int cg  = bid & 3;              // output cols [cg*64, cg*64+64)
    const int t   = threadIdx.x;
    const int g   = t >> 6;               // wave id == k/v group, 0..7
    const int c   = t & 63;

    const float4* emb4 = reinterpret_cast<const float4*>(emb);
    const float4* W14  = reinterpret_cast<const float4*>(W1);

    // ---- (1) X row reads first (histogram depends only on these) ----
    const int   vl    = valid_lens[b];
    const int4* xrow4 = reinterpret_cast<const int4*>(X + (size_t)b * L_SZ);
    const int4  t0    = xrow4[t];
    const int4  t1    = xrow4[t + NT];

    // ---- (2) W2 slice + emb slice + biases (~40 VMEM ops, < vmcnt cap) ----
    float w2[32];
    #pragma unroll
    for (int q = 0; q < 32; ++q)
        w2[q] = W2[(g * 32 + q) * D_SZ + cg * 64 + c];

    float4 e4[4];
    #pragma unroll
    for (int j = 0; j < 4; ++j)
        e4[j] = emb4[(g * 4 + j) * C + c];
    float4 e32 = make_float4(0.f, 0.f, 0.f, 0.f);
    if (g == 0) e32 = emb4[32 * C + c];

    float4 bias1 = make_float4(0.f, 0.f, 0.f, 0.f);
    if (t < C) bias1 = reinterpret_cast<const float4*>(b1)[t];
    const float bias2 = (t < 64) ? b2[cg * 64 + t] : 0.f;

    // ---- (3) wave-private bin zero: same-wave DS ops are in-order,
    //          so this wave's atomics below need no barrier ----
    if (c < VOCAB) s_cnt[g][c] = 0;

    // ---- (4) histogram atomics (waits only on t0/t1 via partial vmcnt) ----
    const int l0 = t * 4;
    const int l1 = (t + NT) * 4;
    if (l0 + 0 < vl) atomicAdd(&s_cnt[g][t0.x], 1);
    if (l0 + 1 < vl) atomicAdd(&s_cnt[g][t0.y], 1);
    if (l0 + 2 < vl) atomicAdd(&s_cnt[g][t0.z], 1);
    if (l0 + 3 < vl) atomicAdd(&s_cnt[g][t0.w], 1);
    if (l1 + 0 < vl) atomicAdd(&s_cnt[g][t1.x], 1);
    if (l1 + 1 < vl) atomicAdd(&s_cnt[g][t1.y], 1);
    if (l1 + 2 < vl) atomicAdd(&s_cnt[g][t1.z], 1);
    if (l1 + 3 < vl) atomicAdd(&s_cnt[g][t1.w], 1);

    // ---- (5) W1 slice into 128 VGPRs; stream crosses the lgkm barriers ----
    float4 w1[32];
    #pragma unroll
    for (int j = 0; j < 32; ++j)
        w1[j] = W14[(g * 32 + j) * C + c];

    LBAR();   // histogram visible; weight streams still in flight

    // ---- per-thread count gather (LDS broadcast reads) ----
    float cf[4];
    #pragma unroll
    for (int j = 0; j < 4; ++j) {
        int s = 0;
        #pragma unroll
        for (int w = 0; w < NW; ++w) s += s_cnt[w][g * 4 + j];
        cf[j] = (float)s;
    }
    float c32 = 0.f;
    if (g == 0) {
        int s = 0;
        #pragma unroll
        for (int w = 0; w < NW; ++w) s += s_cnt[w][32];
        c32 = (float)s;
    }

    // ---- pooled partial over this wave's vocab slice ----
    float4 p = make_float4(0.f, 0.f, 0.f, 0.f);
    #pragma unroll
    for (int j = 0; j < 4; ++j) {
        p.x = fmaf(cf[j], e4[j].x, p.x);
        p.y = fmaf(cf[j], e4[j].y, p.y);
        p.z = fmaf(cf[j], e4[j].z, p.z);
        p.w = fmaf(cf[j], e4[j].w, p.w);
    }
    p.x = fmaf(c32, e32.x, p.x);
    p.y = fmaf(c32, e32.y, p.y);
    p.z = fmaf(c32, e32.z, p.z);
    p.w = fmaf(c32, e32.w, p.w);
    s_part[g][c] = p;
    LBAR();

    if (t < C) {
        float4 s = s_part[0][t];
        #pragma unroll
        for (int g2 = 1; g2 < NW; ++g2) {
            float4 q = s_part[g2][t];
            s.x += q.x; s.y += q.y; s.z += q.z; s.w += q.w;
        }
        reinterpret_cast<float4*>(s_vec)[t] = s;
    }
    LBAR();

    // ---- layer 1 from registers: k in [g*32, g*32+32) ----
    // (first use of w1 regs: compiler inserts the only vmcnt wait here)
    float4 acc = make_float4(0.f, 0.f, 0.f, 0.f);
    #pragma unroll
    for (int j = 0; j < 32; ++j) {
        const float sv = s_vec[g * 32 + j];
        acc.x = fmaf(sv, w1[j].x, acc.x);
        acc.y = fmaf(sv, w1[j].y, acc.y);
        acc.z = fmaf(sv, w1[j].z, acc.z);
        acc.w = fmaf(sv, w1[j].w, acc.w);
    }
    s_part[g][c] = acc;
    LBAR();

    if (t < C) {
        float4 h = bias1;
        #pragma unroll
        for (int g2 = 0; g2 < NW; ++g2) {
            float4 q = s_part[g2][t];
            h.x += q.x; h.y += q.y; h.z += q.z; h.w += q.w;
        }
        h.x = fmaxf(h.x, 0.f); h.y = fmaxf(h.y, 0.f);
        h.z = fmaxf(h.z, 0.f); h.w = fmaxf(h.w, 0.f);
        reinterpret_cast<float4*>(s_vec)[t] = h;
    }
    LBAR();

    // ---- layer 2 from registers: 64-column slice, k-split 8 ----
    float acc2 = 0.f;
    #pragma unroll
    for (int q = 0; q < 32; ++q)
        acc2 = fmaf(s_vec[g * 32 + q], w2[q], acc2);
    ((float*)s_part)[g * 64 + c] = acc2;
    LBAR();

    if (t < 64) {
        float o = bias2;
        #pragma unroll
        for (int q = 0; q < NW; ++q) o += ((float*)s_part)[q * 64 + t];
        out[(size_t)b * D_SZ + cg * 64 + t] = fmaxf(o, 0.f);
    }
}

extern "C" void kernel_launch(void* const* d_in, const int* in_sizes, int n_in,
                              void* d_out, int out_size, void* d_ws, size_t ws_size,
                              hipStream_t stream) {
    const int*   X          = (const int*)d_in[0];
    const int*   valid_lens = (const int*)d_in[1];
    const float* emb        = (const float*)d_in[2];
    const float* W1         = (const float*)d_in[3];
    const float* b1         = (const float*)d_in[4];
    const float* W2         = (const float*)d_in[5];
    const float* b2         = (const float*)d_in[6];
    float* out = (float*)d_out;

    prot_fused<<<256, NT, 0, stream>>>(X, valid_lens, emb, W1, b1, W2, b2, out);
}